// Round 6
// baseline (233.402 us; speedup 1.0000x reference)
//
#include <hip/hip_runtime.h>

#define NNODES 100000
#define NEDGES 600000
#define D 128
#define NSUB 8   // sub-chains per (node, dir): e & 7 selects the class

typedef short bf16x8 __attribute__((ext_vector_type(8)));
typedef float f32x4  __attribute__((ext_vector_type(4)));

__device__ __forceinline__ unsigned short f2bf(float f) {
    unsigned u = __float_as_uint(f);
    unsigned r = (u + 0x7FFFu + ((u >> 16) & 1u)) >> 16;
    return (unsigned short)r;
}
__device__ __forceinline__ float bf2f(unsigned short h) {
    return __uint_as_float(((unsigned)h) << 16);
}

// ---------------------------------------------------------------------------
// x (fp32) -> xb (bf16). 4 elems/thread.
// ---------------------------------------------------------------------------
__global__ __launch_bounds__(256) void k_tobf16(
    const float* __restrict__ x, unsigned short* __restrict__ xb)
{
    int i = blockIdx.x * 256 + threadIdx.x;      // float4 index
    if (i >= NNODES * D / 4) return;
    float4 v = *(const float4*)(x + (size_t)i * 4);
    ushort4 o;
    o.x = f2bf(v.x); o.y = f2bf(v.y); o.z = f2bf(v.z); o.w = f2bf(v.w);
    *(ushort4*)(xb + (size_t)i * 4) = o;
}

// ---------------------------------------------------------------------------
// Weight prep: wcat[0]=wl_f, wcat[1]=wl_b, wcat[2]=wr_f+wr_b (bf16, row-major
// [out_c][in_k]); bb = bl_f + bl_b (fp32).
// ---------------------------------------------------------------------------
__global__ __launch_bounds__(256) void k_wprep(
    const float* __restrict__ wl_f, const float* __restrict__ wl_b,
    const float* __restrict__ wr_f, const float* __restrict__ wr_b,
    const float* __restrict__ bl_f, const float* __restrict__ bl_b,
    unsigned short* __restrict__ wcat, float* __restrict__ bb)
{
    int i = blockIdx.x * 256 + threadIdx.x;
    if (i >= 128 * 128) return;
    wcat[i]             = f2bf(wl_f[i]);
    wcat[16384 + i]     = f2bf(wl_b[i]);
    wcat[32768 + i]     = f2bf(wr_f[i] + wr_b[i]);
    if (i < 128) bb[i] = bl_f[i] + bl_b[i];
}

// ---------------------------------------------------------------------------
// Linked-list adjacency build, 8 sub-chains per (node, dir) keyed by e&7.
//   next_f[e] = atomicExch(&head_f[(e&7)*N + dst], e)
//   next_b[e] = atomicExch(&head_b[(e&7)*N + src], e)
// atomicExch hits L2-resident head arrays (6.4 MB); next[] writes coalesced.
// Each edge is linked exactly once per dir -> chains disjoint & acyclic.
// ---------------------------------------------------------------------------
__global__ __launch_bounds__(256) void k_build(
    const int* __restrict__ ei,
    int* __restrict__ head_f, int* __restrict__ next_f,
    int* __restrict__ head_b, int* __restrict__ next_b)
{
    int e = blockIdx.x * 256 + threadIdx.x;
    if (e >= NEDGES) return;
    int s = ei[e];
    int d = ei[NEDGES + e];
    s = min(max(s, 0), NNODES - 1);
    d = min(max(d, 0), NNODES - 1);
    int c = (e & (NSUB - 1)) * NNODES;
    next_f[e] = atomicExch(&head_f[c + d], e);
    next_b[e] = atomicExch(&head_b[c + s], e);
}

// ---------------------------------------------------------------------------
// Chain-walk gather means, 8-way ILP: one 32-lane group per (node, dir)
// advances 8 independent sub-chain cursors per iteration (8 gathers + 8
// next-loads in flight; dependent-chain depth ~ Poisson(6)/8 max ~ 2-3).
// All sub-chains accumulate into the same registers. Lane owns 4 columns.
// Writes bf16 means interleaved into d_out:
//   meanpair[n] = { mean_f[n] (256B) , mean_b[n] (256B) }
// ---------------------------------------------------------------------------
__global__ __launch_bounds__(256) void k_mean(
    const unsigned short* __restrict__ xb, const int* __restrict__ ei,
    const int* __restrict__ head_f, const int* __restrict__ next_f,
    const int* __restrict__ head_b, const int* __restrict__ next_b,
    unsigned short* __restrict__ meanpair)   // [N][256] bf16
{
    int g = (blockIdx.x * 256 + threadIdx.x) >> 5;
    int lane = threadIdx.x & 31;
    if (g >= 2 * NNODES) return;
    const int dir = (g >= NNODES);
    const int n = dir ? g - NNODES : g;
    const int* head = dir ? head_b : head_f;
    const int* next = dir ? next_b : next_f;
    const int* nbrs = dir ? ei + NEDGES : ei;

    int e[NSUB];
#pragma unroll
    for (int c = 0; c < NSUB; ++c) e[c] = head[c * NNODES + n];

    float a0 = 0.f, a1 = 0.f, a2 = 0.f, a3 = 0.f;
    int cnt = 0;
    bool any = false;
#pragma unroll
    for (int c = 0; c < NSUB; ++c) any = any || (e[c] >= 0);

    for (int it = 0; it < NEDGES && any; ++it) {
#pragma unroll
        for (int c = 0; c < NSUB; ++c) {
            int ec = e[c];
            if (ec >= 0) {
                int nbr = nbrs[ec];
                nbr = min(max(nbr, 0), NNODES - 1);
                ushort4 v = *(const ushort4*)(xb + (size_t)nbr * D + lane * 4);
                a0 += bf2f(v.x); a1 += bf2f(v.y); a2 += bf2f(v.z); a3 += bf2f(v.w);
                ++cnt;
                e[c] = next[ec];
            }
        }
        any = false;
#pragma unroll
        for (int c = 0; c < NSUB; ++c) any = any || (e[c] >= 0);
    }

    float sc = 1.0f / (float)max(cnt, 1);
    ushort4 o;
    o.x = f2bf(a0 * sc); o.y = f2bf(a1 * sc); o.z = f2bf(a2 * sc); o.w = f2bf(a3 * sc);
    *(ushort4*)(meanpair + (size_t)n * 256 + dir * 128 + lane * 4) = o;
}

// ---------------------------------------------------------------------------
// MFMA GEMM + bias + relu (unchanged).
// out[N,128] = relu(0.5*( A @ Wcat^T-concat + bb )), A k-segs:
//   seg0 = mean_f (bf16, in d_out), seg1 = mean_b (bf16, in d_out), seg2 = xb.
// 128x128 tile / block, 4 waves (2x2 of 64x64), 16x16x32 bf16 MFMA, BK=64.
// LDS XOR-swizzle (byte ^= (row&7)<<4) for conflict-free ds_read_b128.
// d_out aliasing: block reads only its own 128 rows' meanpairs and writes
// exactly those bytes in the epilogue.
// ---------------------------------------------------------------------------
__global__ __launch_bounds__(256) void gemm_mfma(
    const unsigned char* __restrict__ meanpair,  // [N][512B]
    const unsigned char* __restrict__ xb,        // [N][256B]
    const unsigned char* __restrict__ wcat,      // [3][128][256B]
    const float* __restrict__ bb,
    float* __restrict__ out)
{
    __shared__ uint4 As4[1024];   // 128 rows x 128B (64 bf16), swizzled
    __shared__ uint4 Ws4[1024];
    unsigned char* Asm = (unsigned char*)As4;
    unsigned char* Wsm = (unsigned char*)Ws4;

    const int tid = threadIdx.x;
    const int n0 = blockIdx.x * 128;
    const int wv = tid >> 6;
    const int wr = wv >> 1, wc = wv & 1;
    const int lane = tid & 63;
    const int l15 = lane & 15, l4 = lane >> 4;

    f32x4 acc[4][4];
#pragma unroll
    for (int i = 0; i < 4; ++i)
#pragma unroll
        for (int j = 0; j < 4; ++j)
            acc[i][j] = (f32x4){0.f, 0.f, 0.f, 0.f};

    for (int kstep = 0; kstep < 6; ++kstep) {
        const int seg  = kstep >> 1;
        const int ks0b = (kstep & 1) * 128;   // byte offset into seg's 256B k-range
        __syncthreads();
        // stage A tile: 128 rows x 128B, 1024 16B-chunks, 4/thread
#pragma unroll
        for (int t = 0; t < 4; ++t) {
            int ch  = tid + t * 256;
            int row = ch >> 3;
            int kb  = (ch & 7) << 4;
            int rowg = n0 + row;
            uint4 v = make_uint4(0u, 0u, 0u, 0u);
            if (rowg < NNODES) {
                const unsigned char* src = (seg < 2)
                    ? meanpair + (size_t)rowg * 512 + seg * 256 + ks0b + kb
                    : xb + (size_t)rowg * 256 + ks0b + kb;
                v = *(const uint4*)src;
            }
            *(uint4*)(Asm + row * 128 + (kb ^ ((row & 7) << 4))) = v;
        }
        // stage W tile: 128 c-rows x 128B
#pragma unroll
        for (int t = 0; t < 4; ++t) {
            int ch = tid + t * 256;
            int c  = ch >> 3;
            int kb = (ch & 7) << 4;
            const unsigned char* src = wcat + seg * 32768 + (size_t)c * 256 + ks0b + kb;
            *(uint4*)(Wsm + c * 128 + (kb ^ ((c & 7) << 4))) = *(const uint4*)src;
        }
        __syncthreads();
        // compute: two K=32 slabs
#pragma unroll
        for (int ks = 0; ks < 2; ++ks) {
            const int kb = ks * 64 + l4 * 16;
            bf16x8 af[4], bf[4];
#pragma unroll
            for (int i = 0; i < 4; ++i) {
                int row = wr * 64 + i * 16 + l15;
                af[i] = *(const bf16x8*)(Asm + row * 128 + (kb ^ ((row & 7) << 4)));
            }
#pragma unroll
            for (int j = 0; j < 4; ++j) {
                int c = wc * 64 + j * 16 + l15;
                bf[j] = *(const bf16x8*)(Wsm + c * 128 + (kb ^ ((c & 7) << 4)));
            }
#pragma unroll
            for (int i = 0; i < 4; ++i)
#pragma unroll
                for (int j = 0; j < 4; ++j)
                    acc[i][j] = __builtin_amdgcn_mfma_f32_16x16x32_bf16(
                        af[i], bf[j], acc[i][j], 0, 0, 0);
        }
    }

    // epilogue: D-tile mapping col=lane&15, row=(lane>>4)*4+r
#pragma unroll
    for (int i = 0; i < 4; ++i) {
        int row0 = n0 + wr * 64 + i * 16 + l4 * 4;
#pragma unroll
        for (int j = 0; j < 4; ++j) {
            int col = wc * 64 + j * 16 + l15;
            float b = bb[col];
#pragma unroll
            for (int r = 0; r < 4; ++r) {
                int row = row0 + r;
                if (row < NNODES) {
                    float v = 0.5f * (acc[i][j][r] + b);
                    out[(size_t)row * 128 + col] = v > 0.f ? v : 0.f;
                }
            }
        }
    }
}

extern "C" void kernel_launch(void* const* d_in, const int* in_sizes, int n_in,
                              void* d_out, int out_size, void* d_ws, size_t ws_size,
                              hipStream_t stream)
{
    const float* x  = (const float*)d_in[0];
    const int*   ei = (const int*)d_in[1];   // int64 in reference -> int32 here
    const float* wl_f = (const float*)d_in[3];
    const float* bl_f = (const float*)d_in[4];
    const float* wr_f = (const float*)d_in[5];
    const float* wl_b = (const float*)d_in[6];
    const float* bl_b = (const float*)d_in[7];
    const float* wr_b = (const float*)d_in[8];
    float* out = (float*)d_out;

    // ws layout (~37 MB): xb | wcat | bb | head_f[8][N] | head_b[8][N] |
    //                     next_f | next_b
    unsigned short* xb   = (unsigned short*)d_ws;                 // N*D bf16
    unsigned short* wcat = xb + (size_t)NNODES * D;               // 3*128*128
    float* bb   = (float*)(wcat + 3 * 128 * 128);                 // 128
    int* head_f = (int*)(bb + 128);                               // NSUB*N
    int* head_b = head_f + (size_t)NSUB * NNODES;                 // NSUB*N
    int* next_f = head_b + (size_t)NSUB * NNODES;
    int* next_b = next_f + NEDGES;
    unsigned short* meanpair = (unsigned short*)d_out;  // [N][256] bf16, overwritten by gemm

    // head_* = -1
    hipMemsetAsync(head_f, 0xFF, 2 * (size_t)NSUB * NNODES * sizeof(int), stream);

    dim3 b256(256);
    dim3 gE((NEDGES + 255) / 256);

    k_tobf16<<<dim3((NNODES * D / 4 + 255) / 256), b256, 0, stream>>>(x, xb);
    k_wprep<<<dim3(64), b256, 0, stream>>>(wl_f, wl_b, wr_f, wr_b, bl_f, bl_b, wcat, bb);
    k_build<<<gE, b256, 0, stream>>>(ei, head_f, next_f, head_b, next_b);

    dim3 gMean(((size_t)2 * NNODES * 32 + 255) / 256);
    k_mean<<<gMean, b256, 0, stream>>>(xb, ei, head_f, next_f, head_b, next_b, meanpair);

    dim3 gG((NNODES + 127) / 128);
    gemm_mfma<<<gG, b256, 0, stream>>>((const unsigned char*)meanpair,
                                       (const unsigned char*)xb,
                                       (const unsigned char*)wcat, bb, out);
}

// Round 7
// 208.577 us; speedup vs baseline: 1.1190x; 1.1190x over previous
//
#include <hip/hip_runtime.h>

#define NNODES 100000
#define NEDGES 600000
#define D 128

typedef short bf16x8 __attribute__((ext_vector_type(8)));
typedef float f32x4  __attribute__((ext_vector_type(4)));

// block-range split for the fused prep kernel
#define TOBF_BLOCKS 12500            // 3.2M float4 / 256
#define BUILD_BLOCKS 2344            // ceil(600000/256)
#define WPREP_BLOCKS 64              // 16384/256
#define PREP_BLOCKS (TOBF_BLOCKS + BUILD_BLOCKS + WPREP_BLOCKS)

__device__ __forceinline__ unsigned short f2bf(float f) {
    unsigned u = __float_as_uint(f);
    unsigned r = (u + 0x7FFFu + ((u >> 16) & 1u)) >> 16;
    return (unsigned short)r;
}
__device__ __forceinline__ float bf2f(unsigned short h) {
    return __uint_as_float(((unsigned)h) << 16);
}

// ---------------------------------------------------------------------------
// Fused prep: three independent jobs, selected by block range, so they
// co-schedule (build's atomic latency hides under tobf16's BW stream).
//   job A (12500 blocks): x fp32 -> xb bf16 (float4/thread)
//   job B (2344 blocks):  linked-list adjacency build
//       next_f[e] = atomicExch(&head_f[dst], e)  (chain of in-edges of dst)
//       next_b[e] = atomicExch(&head_b[src], e)  (chain of out-edges of src)
//     heads pre-set to -1; chains disjoint & acyclic by construction.
//   job C (64 blocks):    weights -> bf16 wcat {wl_f, wl_b, wr_f+wr_b}; bias
// ---------------------------------------------------------------------------
__global__ __launch_bounds__(256) void k_prep(
    const float* __restrict__ x, const int* __restrict__ ei,
    const float* __restrict__ wl_f, const float* __restrict__ wl_b,
    const float* __restrict__ wr_f, const float* __restrict__ wr_b,
    const float* __restrict__ bl_f, const float* __restrict__ bl_b,
    unsigned short* __restrict__ xb,
    int* __restrict__ head_f, int* __restrict__ next_f,
    int* __restrict__ head_b, int* __restrict__ next_b,
    unsigned short* __restrict__ wcat, float* __restrict__ bb)
{
    const int b = blockIdx.x;
    if (b < TOBF_BLOCKS) {
        int i = b * 256 + threadIdx.x;            // float4 index
        if (i >= NNODES * D / 4) return;
        float4 v = *(const float4*)(x + (size_t)i * 4);
        ushort4 o;
        o.x = f2bf(v.x); o.y = f2bf(v.y); o.z = f2bf(v.z); o.w = f2bf(v.w);
        *(ushort4*)(xb + (size_t)i * 4) = o;
    } else if (b < TOBF_BLOCKS + BUILD_BLOCKS) {
        int e = (b - TOBF_BLOCKS) * 256 + threadIdx.x;
        if (e >= NEDGES) return;
        int s = ei[e];
        int d = ei[NEDGES + e];
        s = min(max(s, 0), NNODES - 1);
        d = min(max(d, 0), NNODES - 1);
        next_f[e] = atomicExch(&head_f[d], e);
        next_b[e] = atomicExch(&head_b[s], e);
    } else {
        int i = (b - TOBF_BLOCKS - BUILD_BLOCKS) * 256 + threadIdx.x;
        if (i >= 128 * 128) return;
        wcat[i]         = f2bf(wl_f[i]);
        wcat[16384 + i] = f2bf(wl_b[i]);
        wcat[32768 + i] = f2bf(wr_f[i] + wr_b[i]);
        if (i < 128) bb[i] = bl_f[i] + bl_b[i];
    }
}

// ---------------------------------------------------------------------------
// Chain-walk gather means over bf16 x (round-5 proven version). One 32-lane
// group per (node, dir); lane owns 4 columns (8B). Neighbor id from ei:
//   forward chain (grouped by dst): neighbor = ei[e]        (src)
//   backward chain (grouped by src): neighbor = ei[NEDGES+e] (dst)
// Writes bf16 means interleaved into d_out:
//   meanpair[n] = { mean_f[n] (256B) , mean_b[n] (256B) }
// Bound by random-gather service BW beyond L2 (~84% L2 miss on 25.6MB set).
// ---------------------------------------------------------------------------
__global__ __launch_bounds__(256) void k_mean(
    const unsigned short* __restrict__ xb, const int* __restrict__ ei,
    const int* __restrict__ head_f, const int* __restrict__ next_f,
    const int* __restrict__ head_b, const int* __restrict__ next_b,
    unsigned short* __restrict__ meanpair)   // [N][256] bf16
{
    int g = (blockIdx.x * 256 + threadIdx.x) >> 5;
    int lane = threadIdx.x & 31;
    if (g >= 2 * NNODES) return;
    const int dir = (g >= NNODES);
    const int n = dir ? g - NNODES : g;
    const int* head = dir ? head_b : head_f;
    const int* next = dir ? next_b : next_f;
    const int* nbrs = dir ? ei + NEDGES : ei;

    float a0 = 0.f, a1 = 0.f, a2 = 0.f, a3 = 0.f;
    int cnt = 0;
    int e = head[n];
    for (int it = 0; it < NEDGES && e >= 0; ++it) {
        int nbr = nbrs[e];
        nbr = min(max(nbr, 0), NNODES - 1);
        ushort4 v = *(const ushort4*)(xb + (size_t)nbr * D + lane * 4);
        a0 += bf2f(v.x); a1 += bf2f(v.y); a2 += bf2f(v.z); a3 += bf2f(v.w);
        ++cnt;
        e = next[e];
    }
    float sc = 1.0f / (float)max(cnt, 1);
    ushort4 o;
    o.x = f2bf(a0 * sc); o.y = f2bf(a1 * sc); o.z = f2bf(a2 * sc); o.w = f2bf(a3 * sc);
    *(ushort4*)(meanpair + (size_t)n * 256 + dir * 128 + lane * 4) = o;
}

// ---------------------------------------------------------------------------
// MFMA GEMM + bias + relu (unchanged).
// out[N,128] = relu(0.5*( A @ Wcat^T-concat + bb )), A k-segs:
//   seg0 = mean_f (bf16, in d_out), seg1 = mean_b (bf16, in d_out), seg2 = xb.
// 128x128 tile / block, 4 waves (2x2 of 64x64), 16x16x32 bf16 MFMA, BK=64.
// LDS XOR-swizzle (byte ^= (row&7)<<4) for conflict-free ds_read_b128.
// d_out aliasing: block reads only its own 128 rows' meanpairs and writes
// exactly those bytes in the epilogue.
// ---------------------------------------------------------------------------
__global__ __launch_bounds__(256) void gemm_mfma(
    const unsigned char* __restrict__ meanpair,  // [N][512B]
    const unsigned char* __restrict__ xb,        // [N][256B]
    const unsigned char* __restrict__ wcat,      // [3][128][256B]
    const float* __restrict__ bb,
    float* __restrict__ out)
{
    __shared__ uint4 As4[1024];   // 128 rows x 128B (64 bf16), swizzled
    __shared__ uint4 Ws4[1024];
    unsigned char* Asm = (unsigned char*)As4;
    unsigned char* Wsm = (unsigned char*)Ws4;

    const int tid = threadIdx.x;
    const int n0 = blockIdx.x * 128;
    const int wv = tid >> 6;
    const int wr = wv >> 1, wc = wv & 1;
    const int lane = tid & 63;
    const int l15 = lane & 15, l4 = lane >> 4;

    f32x4 acc[4][4];
#pragma unroll
    for (int i = 0; i < 4; ++i)
#pragma unroll
        for (int j = 0; j < 4; ++j)
            acc[i][j] = (f32x4){0.f, 0.f, 0.f, 0.f};

    for (int kstep = 0; kstep < 6; ++kstep) {
        const int seg  = kstep >> 1;
        const int ks0b = (kstep & 1) * 128;   // byte offset into seg's 256B k-range
        __syncthreads();
        // stage A tile: 128 rows x 128B, 1024 16B-chunks, 4/thread
#pragma unroll
        for (int t = 0; t < 4; ++t) {
            int ch  = tid + t * 256;
            int row = ch >> 3;
            int kb  = (ch & 7) << 4;
            int rowg = n0 + row;
            uint4 v = make_uint4(0u, 0u, 0u, 0u);
            if (rowg < NNODES) {
                const unsigned char* src = (seg < 2)
                    ? meanpair + (size_t)rowg * 512 + seg * 256 + ks0b + kb
                    : xb + (size_t)rowg * 256 + ks0b + kb;
                v = *(const uint4*)src;
            }
            *(uint4*)(Asm + row * 128 + (kb ^ ((row & 7) << 4))) = v;
        }
        // stage W tile: 128 c-rows x 128B
#pragma unroll
        for (int t = 0; t < 4; ++t) {
            int ch = tid + t * 256;
            int c  = ch >> 3;
            int kb = (ch & 7) << 4;
            const unsigned char* src = wcat + seg * 32768 + (size_t)c * 256 + ks0b + kb;
            *(uint4*)(Wsm + c * 128 + (kb ^ ((c & 7) << 4))) = *(const uint4*)src;
        }
        __syncthreads();
        // compute: two K=32 slabs
#pragma unroll
        for (int ks = 0; ks < 2; ++ks) {
            const int kb = ks * 64 + l4 * 16;
            bf16x8 af[4], bf[4];
#pragma unroll
            for (int i = 0; i < 4; ++i) {
                int row = wr * 64 + i * 16 + l15;
                af[i] = *(const bf16x8*)(Asm + row * 128 + (kb ^ ((row & 7) << 4)));
            }
#pragma unroll
            for (int j = 0; j < 4; ++j) {
                int c = wc * 64 + j * 16 + l15;
                bf[j] = *(const bf16x8*)(Wsm + c * 128 + (kb ^ ((c & 7) << 4)));
            }
#pragma unroll
            for (int i = 0; i < 4; ++i)
#pragma unroll
                for (int j = 0; j < 4; ++j)
                    acc[i][j] = __builtin_amdgcn_mfma_f32_16x16x32_bf16(
                        af[i], bf[j], acc[i][j], 0, 0, 0);
        }
    }

    // epilogue: D-tile mapping col=lane&15, row=(lane>>4)*4+r
#pragma unroll
    for (int i = 0; i < 4; ++i) {
        int row0 = n0 + wr * 64 + i * 16 + l4 * 4;
#pragma unroll
        for (int j = 0; j < 4; ++j) {
            int col = wc * 64 + j * 16 + l15;
            float b = bb[col];
#pragma unroll
            for (int r = 0; r < 4; ++r) {
                int row = row0 + r;
                if (row < NNODES) {
                    float v = 0.5f * (acc[i][j][r] + b);
                    out[(size_t)row * 128 + col] = v > 0.f ? v : 0.f;
                }
            }
        }
    }
}

extern "C" void kernel_launch(void* const* d_in, const int* in_sizes, int n_in,
                              void* d_out, int out_size, void* d_ws, size_t ws_size,
                              hipStream_t stream)
{
    const float* x  = (const float*)d_in[0];
    const int*   ei = (const int*)d_in[1];   // int64 in reference -> int32 here
    const float* wl_f = (const float*)d_in[3];
    const float* bl_f = (const float*)d_in[4];
    const float* wr_f = (const float*)d_in[5];
    const float* wl_b = (const float*)d_in[6];
    const float* bl_b = (const float*)d_in[7];
    const float* wr_b = (const float*)d_in[8];
    float* out = (float*)d_out;

    // ws layout (~31.3 MB): xb | wcat | bb | head_f | head_b | next_f | next_b
    unsigned short* xb   = (unsigned short*)d_ws;                 // N*D bf16
    unsigned short* wcat = xb + (size_t)NNODES * D;               // 3*128*128
    float* bb   = (float*)(wcat + 3 * 128 * 128);                 // 128
    int* head_f = (int*)(bb + 128);
    int* head_b = head_f + NNODES;
    int* next_f = head_b + NNODES;
    int* next_b = next_f + NEDGES;
    unsigned short* meanpair = (unsigned short*)d_out;  // [N][256] bf16, overwritten by gemm

    // head_* = -1
    hipMemsetAsync(head_f, 0xFF, 2 * (size_t)NNODES * sizeof(int), stream);

    dim3 b256(256);
    k_prep<<<dim3(PREP_BLOCKS), b256, 0, stream>>>(
        x, ei, wl_f, wl_b, wr_f, wr_b, bl_f, bl_b,
        xb, head_f, next_f, head_b, next_b, wcat, bb);

    dim3 gMean(((size_t)2 * NNODES * 32 + 255) / 256);
    k_mean<<<gMean, b256, 0, stream>>>(xb, ei, head_f, next_f, head_b, next_b, meanpair);

    dim3 gG((NNODES + 127) / 128);
    gemm_mfma<<<gG, b256, 0, stream>>>((const unsigned char*)meanpair,
                                       (const unsigned char*)xb,
                                       (const unsigned char*)wcat, bb, out);
}

// Round 8
// 187.005 us; speedup vs baseline: 1.2481x; 1.1154x over previous
//
#include <hip/hip_runtime.h>

#define NNODES 100000
#define NEDGES 600000
#define D 128

typedef short bf16x8 __attribute__((ext_vector_type(8)));
typedef float f32x4  __attribute__((ext_vector_type(4)));

// interleaved role split for the fused prep kernel: every 6th block is a
// build block so build co-resides with tobf16 for the whole dispatch.
#define PREP_BLOCKS 15000   // bb=b/6 in [0,2500), rem=b%6
                            // rem<5  -> tobf16 t = bb*5+rem   (12500 blocks)
                            // rem==5 -> bb<2344: build bb; bb in [2344,2408): wprep

__device__ __forceinline__ unsigned short f2bf(float f) {
    unsigned u = __float_as_uint(f);
    unsigned r = (u + 0x7FFFu + ((u >> 16) & 1u)) >> 16;
    return (unsigned short)r;
}
__device__ __forceinline__ float bf2f(unsigned short h) {
    return __uint_as_float(((unsigned)h) << 16);
}

// wave-collective async global->LDS, 16B/lane (dest = uniform base + lane*16)
__device__ __forceinline__ void gl_lds16(const unsigned char* g, unsigned char* l) {
    __builtin_amdgcn_global_load_lds(
        (const __attribute__((address_space(1))) unsigned int*)g,
        (__attribute__((address_space(3))) unsigned int*)l, 16, 0, 0);
}

// ---------------------------------------------------------------------------
// Fused prep, role-interleaved:
//   tobf16: x fp32 -> xb bf16 (float4/thread)
//   build:  linked-list adjacency: next_f[e]=atomicExch(&head_f[dst],e),
//           next_b[e]=atomicExch(&head_b[src],e); heads pre-set to -1.
//   wprep:  weights -> bf16 wcat {wl_f, wl_b, wr_f+wr_b}; bias sum.
// ---------------------------------------------------------------------------
__global__ __launch_bounds__(256) void k_prep(
    const float* __restrict__ x, const int* __restrict__ ei,
    const float* __restrict__ wl_f, const float* __restrict__ wl_b,
    const float* __restrict__ wr_f, const float* __restrict__ wr_b,
    const float* __restrict__ bl_f, const float* __restrict__ bl_b,
    unsigned short* __restrict__ xb,
    int* __restrict__ head_f, int* __restrict__ next_f,
    int* __restrict__ head_b, int* __restrict__ next_b,
    unsigned short* __restrict__ wcat, float* __restrict__ bb)
{
    const int b = blockIdx.x;
    const int bb6 = b / 6;
    const int rem = b - bb6 * 6;
    if (rem < 5) {
        int t = bb6 * 5 + rem;                    // [0,12500)
        int i = t * 256 + threadIdx.x;            // float4 index
        if (i >= NNODES * D / 4) return;
        float4 v = *(const float4*)(x + (size_t)i * 4);
        ushort4 o;
        o.x = f2bf(v.x); o.y = f2bf(v.y); o.z = f2bf(v.z); o.w = f2bf(v.w);
        *(ushort4*)(xb + (size_t)i * 4) = o;
    } else if (bb6 < 2344) {
        int e = bb6 * 256 + threadIdx.x;
        if (e >= NEDGES) return;
        int s = ei[e];
        int d = ei[NEDGES + e];
        s = min(max(s, 0), NNODES - 1);
        d = min(max(d, 0), NNODES - 1);
        next_f[e] = atomicExch(&head_f[d], e);
        next_b[e] = atomicExch(&head_b[s], e);
    } else if (bb6 < 2408) {
        int i = (bb6 - 2344) * 256 + threadIdx.x;
        if (i >= 128 * 128) return;
        wcat[i]         = f2bf(wl_f[i]);
        wcat[16384 + i] = f2bf(wl_b[i]);
        wcat[32768 + i] = f2bf(wr_f[i] + wr_b[i]);
        if (i < 128) bb[i] = bl_f[i] + bl_b[i];
    }
}

// ---------------------------------------------------------------------------
// Chain-walk gather means over bf16 x (proven round-5 version, untouched).
// One 32-lane group per (node, dir); lane owns 4 columns (8B).
// Bound by random-gather service BW beyond L2 (FETCH ~= 8-XCD compulsory).
// Writes bf16 means interleaved into d_out:
//   meanpair[n] = { mean_f[n] (256B) , mean_b[n] (256B) }
// ---------------------------------------------------------------------------
__global__ __launch_bounds__(256) void k_mean(
    const unsigned short* __restrict__ xb, const int* __restrict__ ei,
    const int* __restrict__ head_f, const int* __restrict__ next_f,
    const int* __restrict__ head_b, const int* __restrict__ next_b,
    unsigned short* __restrict__ meanpair)   // [N][256] bf16
{
    int g = (blockIdx.x * 256 + threadIdx.x) >> 5;
    int lane = threadIdx.x & 31;
    if (g >= 2 * NNODES) return;
    const int dir = (g >= NNODES);
    const int n = dir ? g - NNODES : g;
    const int* head = dir ? head_b : head_f;
    const int* next = dir ? next_b : next_f;
    const int* nbrs = dir ? ei + NEDGES : ei;

    float a0 = 0.f, a1 = 0.f, a2 = 0.f, a3 = 0.f;
    int cnt = 0;
    int e = head[n];
    for (int it = 0; it < NEDGES && e >= 0; ++it) {
        int nbr = nbrs[e];
        nbr = min(max(nbr, 0), NNODES - 1);
        ushort4 v = *(const ushort4*)(xb + (size_t)nbr * D + lane * 4);
        a0 += bf2f(v.x); a1 += bf2f(v.y); a2 += bf2f(v.z); a3 += bf2f(v.w);
        ++cnt;
        e = next[e];
    }
    float sc = 1.0f / (float)max(cnt, 1);
    ushort4 o;
    o.x = f2bf(a0 * sc); o.y = f2bf(a1 * sc); o.z = f2bf(a2 * sc); o.w = f2bf(a3 * sc);
    *(ushort4*)(meanpair + (size_t)n * 256 + dir * 128 + lane * 4) = o;
}

// ---------------------------------------------------------------------------
// MFMA GEMM + bias + relu, global_load_lds staging.
// out[N,128] = relu(0.5*( A @ Wcat^T-concat + bb )), A k-segs:
//   seg0 = mean_f (bf16, in d_out), seg1 = mean_b (bf16, in d_out), seg2 = xb.
// 128x128 tile / block, 4 waves (2x2 of 64x64), 16x16x32 bf16 MFMA, BK=64.
// Staging is async global->LDS with LINEAR LDS dest; the XOR bank-swizzle
// (byte ^= (row&7)<<4) is applied to the per-lane GLOBAL source address
// (rule: swizzle both sides via pre-swizzled source, keep dest linear).
// Per-lane source column offset = ((l&7) ^ (l>>3)) << 4 (row&7 == l>>3 since
// n0, wave and t offsets are multiples of 8). OOB rows clamp to row N-1;
// their garbage acc rows are discarded in the epilogue (MFMA rows are
// independent). d_out aliasing: block reads only its own 128 rows' meanpairs
// and writes exactly those bytes in the epilogue.
// ---------------------------------------------------------------------------
__global__ __launch_bounds__(256) void gemm_mfma(
    const unsigned char* __restrict__ meanpair,  // [N][512B]
    const unsigned char* __restrict__ xb,        // [N][256B]
    const unsigned char* __restrict__ wcat,      // [3][128][256B]
    const float* __restrict__ bb,
    float* __restrict__ out)
{
    __shared__ unsigned char Asm[16384];   // 128 rows x 128B, swizzled layout
    __shared__ unsigned char Wsm[16384];

    const int tid = threadIdx.x;
    const int n0 = blockIdx.x * 128;
    const int wv = tid >> 6;
    const int wr = wv >> 1, wc = wv & 1;
    const int lane = tid & 63;
    const int l15 = lane & 15, l4 = lane >> 4;
    const int rowl = lane >> 3;                       // 0..7 within 8-row chunk
    const int xorcol = (((lane & 7) ^ rowl) << 4);    // pre-swizzled source col

    f32x4 acc[4][4];
#pragma unroll
    for (int i = 0; i < 4; ++i)
#pragma unroll
        for (int j = 0; j < 4; ++j)
            acc[i][j] = (f32x4){0.f, 0.f, 0.f, 0.f};

    for (int kstep = 0; kstep < 6; ++kstep) {
        const int seg  = kstep >> 1;
        const int ks0b = (kstep & 1) * 128;   // byte offset into seg's 256B k-range
        __syncthreads();                      // all waves done reading LDS
        // stage A: wave wv covers rows [wv*32, wv*32+32), 4 x 1KB DMA
#pragma unroll
        for (int t = 0; t < 4; ++t) {
            int row = n0 + wv * 32 + t * 8 + rowl;
            int rowc = min(row, NNODES - 1);
            const unsigned char* src = (seg < 2)
                ? meanpair + (size_t)rowc * 512 + seg * 256 + ks0b + xorcol
                : xb + (size_t)rowc * 256 + ks0b + xorcol;
            gl_lds16(src, Asm + wv * 4096 + t * 1024);
        }
        // stage W: same pattern over the 128 output-channel rows
#pragma unroll
        for (int t = 0; t < 4; ++t) {
            int c = wv * 32 + t * 8 + rowl;
            const unsigned char* src =
                wcat + seg * 32768 + (size_t)c * 256 + ks0b + xorcol;
            gl_lds16(src, Wsm + wv * 4096 + t * 1024);
        }
        __syncthreads();                      // drains vmcnt (DMA complete)
        // compute: two K=32 slabs
#pragma unroll
        for (int ks = 0; ks < 2; ++ks) {
            const int kb = ks * 64 + l4 * 16;
            bf16x8 af[4], bf[4];
#pragma unroll
            for (int i = 0; i < 4; ++i) {
                int row = wr * 64 + i * 16 + l15;
                af[i] = *(const bf16x8*)(Asm + row * 128 + (kb ^ ((row & 7) << 4)));
            }
#pragma unroll
            for (int j = 0; j < 4; ++j) {
                int c = wc * 64 + j * 16 + l15;
                bf[j] = *(const bf16x8*)(Wsm + c * 128 + (kb ^ ((c & 7) << 4)));
            }
#pragma unroll
            for (int i = 0; i < 4; ++i)
#pragma unroll
                for (int j = 0; j < 4; ++j)
                    acc[i][j] = __builtin_amdgcn_mfma_f32_16x16x32_bf16(
                        af[i], bf[j], acc[i][j], 0, 0, 0);
        }
    }

    // epilogue: D-tile mapping col=lane&15, row=(lane>>4)*4+r
#pragma unroll
    for (int i = 0; i < 4; ++i) {
        int row0 = n0 + wr * 64 + i * 16 + l4 * 4;
#pragma unroll
        for (int j = 0; j < 4; ++j) {
            int col = wc * 64 + j * 16 + l15;
            float b = bb[col];
#pragma unroll
            for (int r = 0; r < 4; ++r) {
                int row = row0 + r;
                if (row < NNODES) {
                    float v = 0.5f * (acc[i][j][r] + b);
                    out[(size_t)row * 128 + col] = v > 0.f ? v : 0.f;
                }
            }
        }
    }
}

extern "C" void kernel_launch(void* const* d_in, const int* in_sizes, int n_in,
                              void* d_out, int out_size, void* d_ws, size_t ws_size,
                              hipStream_t stream)
{
    const float* x  = (const float*)d_in[0];
    const int*   ei = (const int*)d_in[1];   // int64 in reference -> int32 here
    const float* wl_f = (const float*)d_in[3];
    const float* bl_f = (const float*)d_in[4];
    const float* wr_f = (const float*)d_in[5];
    const float* wl_b = (const float*)d_in[6];
    const float* bl_b = (const float*)d_in[7];
    const float* wr_b = (const float*)d_in[8];
    float* out = (float*)d_out;

    // ws layout (~31.3 MB): xb | wcat | bb | head_f | head_b | next_f | next_b
    unsigned short* xb   = (unsigned short*)d_ws;                 // N*D bf16
    unsigned short* wcat = xb + (size_t)NNODES * D;               // 3*128*128
    float* bb   = (float*)(wcat + 3 * 128 * 128);                 // 128
    int* head_f = (int*)(bb + 128);
    int* head_b = head_f + NNODES;
    int* next_f = head_b + NNODES;
    int* next_b = next_f + NEDGES;
    unsigned short* meanpair = (unsigned short*)d_out;  // [N][256] bf16, overwritten by gemm

    // head_* = -1
    hipMemsetAsync(head_f, 0xFF, 2 * (size_t)NNODES * sizeof(int), stream);

    dim3 b256(256);
    k_prep<<<dim3(PREP_BLOCKS), b256, 0, stream>>>(
        x, ei, wl_f, wl_b, wr_f, wr_b, bl_f, bl_b,
        xb, head_f, next_f, head_b, next_b, wcat, bb);

    dim3 gMean(((size_t)2 * NNODES * 32 + 255) / 256);
    k_mean<<<gMean, b256, 0, stream>>>(xb, ei, head_f, next_f, head_b, next_b, meanpair);

    dim3 gG((NNODES + 127) / 128);
    gemm_mfma<<<gG, b256, 0, stream>>>((const unsigned char*)meanpair,
                                       (const unsigned char*)xb,
                                       (const unsigned char*)wcat, bb, out);
}